// Round 3
// baseline (2487.162 us; speedup 1.0000x reference)
//
#include <hip/hip_runtime.h>

#define DEVFN static __device__ __forceinline__

typedef __bf16 bf16;
typedef __bf16 bf16x8 __attribute__((ext_vector_type(8)));
typedef __bf16 bf16x4 __attribute__((ext_vector_type(4)));
typedef float f32x4 __attribute__((ext_vector_type(4)));
typedef short short8 __attribute__((ext_vector_type(8)));

constexpr int Bc = 4, Hn = 16, Sn = 2048, DH = 128, Dn = 2048;
constexpr long MROWS = (long)Bc * Sn;  // 8192

// ---------- MFMA wrapper: dual-signature dispatch ----------
template <typename T, typename C>
DEVFN auto mfma_impl(T a, T b, C c, int)
    -> decltype(__builtin_amdgcn_mfma_f32_16x16x32_bf16(a, b, c, 0, 0, 0)) {
  return __builtin_amdgcn_mfma_f32_16x16x32_bf16(a, b, c, 0, 0, 0);
}
template <typename T, typename C>
DEVFN C mfma_impl(T a, T b, C c, long) {
  return __builtin_amdgcn_mfma_f32_16x16x32_bf16(
      __builtin_bit_cast(short8, a), __builtin_bit_cast(short8, b), c, 0, 0, 0);
}
DEVFN f32x4 MFMA(bf16x8 a, bf16x8 b, f32x4 c) { return mfma_impl(a, b, c, 0); }

// ---------- async global->LDS 16B ----------
DEVFN void gld_lds16(const bf16* g, bf16* s) {
  __builtin_amdgcn_global_load_lds(
      (const __attribute__((address_space(1))) unsigned int*)g,
      (__attribute__((address_space(3))) unsigned int*)s, 16, 0, 0);
}

// Stage a 128x64 bf16 tile (row stride ld elems) into LDS, linear dest,
// source pre-swizzled so reads with byte^((row&7)<<4) are conflict-free.
DEVFN void stage_tile(const bf16* __restrict__ g, long ld, bf16* __restrict__ s) {
  const int t = threadIdx.x;
  const int rr = t >> 3;
  const int cb = (t & 7) * 16;  // byte offset within 128B row
#pragma unroll
  for (int ch = 0; ch < 4; ++ch) {
    const int r = ch * 32 + rr;
    const int scb = cb ^ ((r & 7) << 4);
    gld_lds16(g + (long)r * ld + (scb >> 1), s + r * 64 + (cb >> 1));
  }
}

// Swizzled fragment read: 8 contiguous bf16 at (tile-local row, k element), 64-col tile
DEVFN bf16x8 ldfrag(const bf16* s, int row, int kelem) {
  const int cb = (kelem * 2) ^ ((row & 7) << 4);
  return *(const bf16x8*)(s + row * 64 + (cb >> 1));
}

// 128-col bf16 tile variant (row stride 256 B)
DEVFN bf16x8 ldfrag128(const bf16* s, int row, int kelem) {
  const int cb = (kelem * 2) ^ ((row & 7) << 4);
  return *(const bf16x8*)((const char*)s + row * 256 + cb);
}

// ---------- split / convert ----------
__global__ __launch_bounds__(256) void k_split(const float* __restrict__ x,
                                               bf16* __restrict__ hi,
                                               bf16* __restrict__ lo, long n) {
  long i = ((long)blockIdx.x * blockDim.x + threadIdx.x) * 4;
  if (i >= n) return;
  float4 v = *(const float4*)(x + i);
  float a[4] = {v.x, v.y, v.z, v.w};
  bf16x4 h, l;
#pragma unroll
  for (int t = 0; t < 4; ++t) {
    bf16 hb = (bf16)a[t];
    h[t] = hb;
    l[t] = (bf16)(a[t] - (float)hb);
  }
  *(bf16x4*)(hi + i) = h;
  *(bf16x4*)(lo + i) = l;
}

__global__ __launch_bounds__(256) void k_cvt(const float* __restrict__ x,
                                             bf16* __restrict__ y, long n) {
  long i = ((long)blockIdx.x * blockDim.x + threadIdx.x) * 4;
  if (i >= n) return;
  float4 v = *(const float4*)(x + i);
  bf16x4 h;
  h[0] = (bf16)v.x; h[1] = (bf16)v.y; h[2] = (bf16)v.z; h[3] = (bf16)v.w;
  *(bf16x4*)(y + i) = h;
}

// ---------- generic C = A @ B^T  (both operands row-major, K contiguous) ----------
// PASSES: 1 = plain bf16, 3 = split-bf16 (hi*hi + hi*lo + lo*hi)
// OUTMODE: 0 = split bf16 pair, 1 = bf16, 2 = f32 + bias, 3 = f32
// CAUSAL: per-(b,h) QK^T, skip tiles above diagonal
template <int PASSES, int OUTMODE, bool CAUSAL>
__global__ __launch_bounds__(256) void k_gemm_bt(
    const bf16* __restrict__ Ahi, const bf16* __restrict__ Alo, long ldA,
    const bf16* __restrict__ Bhi, const bf16* __restrict__ Blo, long ldB, int K,
    bf16* __restrict__ obh, bf16* __restrict__ obl, float* __restrict__ of,
    const float* __restrict__ bias, long ldC) {
  const int nt = blockIdx.x, mt = blockIdx.y;
  long aBase = 0, bBase = 0, cBase = 0;
  if constexpr (CAUSAL) {
    if (nt > mt) return;
    const int bhz = blockIdx.z, b = bhz >> 4, h = bhz & 15;
    aBase = (long)b * Sn * ldA + h * DH;
    bBase = (long)b * Sn * ldB + h * DH;
    cBase = (long)bhz * Sn * Sn;
  }
  constexpr int NT = (PASSES == 3) ? 2 : 1;
  __shared__ __align__(16) bf16 sA[NT][128 * 64];
  __shared__ __align__(16) bf16 sB[NT][128 * 64];
  const int tid = threadIdx.x, w = tid >> 6, lane = tid & 63;
  const int wm = (w >> 1) * 64, wn = (w & 1) * 64;
  const int lr = lane & 15, lg = lane >> 4;
  f32x4 acc[4][4] = {};
  const bf16* Ab = Ahi + aBase + (long)mt * 128 * ldA;
  const bf16* Bb = Bhi + bBase + (long)nt * 128 * ldB;
  const bf16* AbL = (PASSES == 3) ? (Alo + aBase + (long)mt * 128 * ldA) : nullptr;
  const bf16* BbL = (PASSES == 3) ? (Blo + bBase + (long)nt * 128 * ldB) : nullptr;

  for (int kt = 0; kt < K; kt += 64) {
    stage_tile(Ab + kt, ldA, sA[0]);
    stage_tile(Bb + kt, ldB, sB[0]);
    if constexpr (PASSES == 3) {
      stage_tile(AbL + kt, ldA, sA[1]);
      stage_tile(BbL + kt, ldB, sB[1]);
    }
    __syncthreads();
#pragma unroll
    for (int kk = 0; kk < 64; kk += 32) {
      bf16x8 ahf[4], bhf[4], alf[4], blf[4];
#pragma unroll
      for (int m = 0; m < 4; ++m) ahf[m] = ldfrag(sA[0], wm + m * 16 + lr, kk + lg * 8);
#pragma unroll
      for (int n = 0; n < 4; ++n) bhf[n] = ldfrag(sB[0], wn + n * 16 + lr, kk + lg * 8);
      if constexpr (PASSES == 3) {
#pragma unroll
        for (int m = 0; m < 4; ++m) alf[m] = ldfrag(sA[1], wm + m * 16 + lr, kk + lg * 8);
#pragma unroll
        for (int n = 0; n < 4; ++n) blf[n] = ldfrag(sB[1], wn + n * 16 + lr, kk + lg * 8);
      }
#pragma unroll
      for (int m = 0; m < 4; ++m)
#pragma unroll
        for (int n = 0; n < 4; ++n) {
          acc[m][n] = MFMA(ahf[m], bhf[n], acc[m][n]);
          if constexpr (PASSES == 3) {
            acc[m][n] = MFMA(ahf[m], blf[n], acc[m][n]);
            acc[m][n] = MFMA(alf[m], bhf[n], acc[m][n]);
          }
        }
    }
    __syncthreads();
  }

#pragma unroll
  for (int m = 0; m < 4; ++m)
#pragma unroll
    for (int n = 0; n < 4; ++n) {
      const int col = nt * 128 + wn + n * 16 + lr;
#pragma unroll
      for (int r = 0; r < 4; ++r) {
        const long row = (long)mt * 128 + wm + m * 16 + lg * 4 + r;
        const float cv = acc[m][n][r];
        const long idx = cBase + row * ldC + col;
        if constexpr (OUTMODE == 0) {
          bf16 hv = (bf16)cv;
          obh[idx] = hv;
          obl[idx] = (bf16)(cv - (float)hv);
        } else if constexpr (OUTMODE == 1) {
          obh[idx] = (bf16)cv;
        } else if constexpr (OUTMODE == 2) {
          of[idx] = cv + bias[col];
        } else {
          of[idx] = cv;
        }
      }
    }
}

// ---------- wave reductions ----------
DEVFN float wred_max(float x) {
#pragma unroll
  for (int o = 32; o > 0; o >>= 1) x = fmaxf(x, __shfl_xor(x, o, 64));
  return x;
}
DEVFN float wred_sum(float x) {
#pragma unroll
  for (int o = 32; o > 0; o >>= 1) x += __shfl_xor(x, o, 64);
  return x;
}

// ---------- fused softmax + weight-write + PV ----------
// Per (qt, bh) block: pass 1 computes per-row max/sum over the causal range
// (reads lower-triangular scores only); pass 2 re-reads each score tile
// (L2-hot), writes normalized fp32 weights in-place (exact zeros above the
// diagonal), stashes bf16 weights in swizzled LDS, and accumulates PV.
__global__ __launch_bounds__(256) void k_wpv(float* __restrict__ wts,
                                             const bf16* __restrict__ vT,
                                             bf16* __restrict__ ctx) {
  const int qt = blockIdx.x;   // 0..15
  const int bh = blockIdx.y;   // 0..63
  const int b = bh >> 4, h = bh & 15;
  const int tid = threadIdx.x, wv = tid >> 6, lane = tid & 63;
  float* Wb = wts + (long)bh * Sn * Sn;
  const bf16* Vb = vT + (long)h * DH * MROWS + (long)b * Sn;

  __shared__ float s_m[128], s_il[128];
  __shared__ __align__(16) bf16 sW[128 * 128];

  // ---- pass 1: per-row stats over cols [0, qi] ----
  for (int rr = 0; rr < 32; ++rr) {
    const int row = wv * 32 + rr;
    const int qi = qt * 128 + row;  // inclusive causal limit
    const float* p = Wb + (long)(qt * 128 + row) * Sn;
    const int L = qi + 1;
    float mx = -__builtin_inff();
    for (int c = lane * 4; c < L; c += 256) {
      float4 x = *(const float4*)(p + c);
      float a[4] = {x.x, x.y, x.z, x.w};
#pragma unroll
      for (int j = 0; j < 4; ++j)
        if (c + j <= qi) mx = fmaxf(mx, a[j]);
    }
    mx = wred_max(mx);
    float sm = 0.f;
    for (int c = lane * 4; c < L; c += 256) {
      float4 x = *(const float4*)(p + c);
      float a[4] = {x.x, x.y, x.z, x.w};
#pragma unroll
      for (int j = 0; j < 4; ++j)
        if (c + j <= qi) sm += __expf(a[j] - mx);
    }
    sm = wred_sum(sm);
    if (lane == 0) {
      s_m[row] = mx;
      s_il[row] = 1.f / sm;
    }
  }
  __syncthreads();

  // ---- pass 2: per k-tile normalize + write + PV ----
  const int lr = lane & 15, lg = lane >> 4;
  const int wm = (wv >> 1) * 64, wn = (wv & 1) * 64;
  const int cg = (tid & 15) * 4;   // col group within tile (fp32 elems)
  const int rbase = tid >> 4;      // 0..15
  f32x4 acc[4][4] = {};

  for (int kt = 0; kt < 16; ++kt) {
    if (kt <= qt) {
      for (int it = 0; it < 8; ++it) {
        const int row = it * 16 + rbase;
        float* pr = Wb + (long)(qt * 128 + row) * Sn + kt * 128 + cg;
        float4 x0 = *(const float4*)pr;
        float4 x1 = *(const float4*)(pr + 64);
        const float m = s_m[row], il = s_il[row];
        float a0[4] = {x0.x, x0.y, x0.z, x0.w};
        float a1[4] = {x1.x, x1.y, x1.z, x1.w};
        bf16x4 b0, b1;
#pragma unroll
        for (int j = 0; j < 4; ++j) {
          float w0 = __expf(a0[j] - m) * il;
          float w1 = __expf(a1[j] - m) * il;
          if (kt == qt) {
            if (cg + j > row) w0 = 0.f;
            if (cg + 64 + j > row) w1 = 0.f;
          }
          a0[j] = w0; a1[j] = w1;
          b0[j] = (bf16)w0; b1[j] = (bf16)w1;
        }
        *(float4*)pr = make_float4(a0[0], a0[1], a0[2], a0[3]);
        *(float4*)(pr + 64) = make_float4(a1[0], a1[1], a1[2], a1[3]);
        const int xr = (row & 7) << 4;
        *(bf16x4*)((char*)sW + row * 256 + ((cg * 2) ^ xr)) = b0;
        *(bf16x4*)((char*)sW + row * 256 + (((cg + 64) * 2) ^ xr)) = b1;
      }
      __syncthreads();
      // PV accumulate over this k-tile
#pragma unroll
      for (int kk = 0; kk < 128; kk += 32) {
        bf16x8 af[4], bf[4];
#pragma unroll
        for (int m = 0; m < 4; ++m) af[m] = ldfrag128(sW, wm + m * 16 + lr, kk + lg * 8);
#pragma unroll
        for (int n = 0; n < 4; ++n)
          bf[n] = *(const bf16x8*)(Vb + (long)(wn + n * 16 + lr) * MROWS + kt * 128 + kk + lg * 8);
#pragma unroll
        for (int m = 0; m < 4; ++m)
#pragma unroll
          for (int n = 0; n < 4; ++n) acc[m][n] = MFMA(af[m], bf[n], acc[m][n]);
      }
      __syncthreads();
    } else {
      // zero tile above the diagonal
      const float4 z = make_float4(0.f, 0.f, 0.f, 0.f);
      for (int it = 0; it < 8; ++it) {
        const int row = it * 16 + rbase;
        float* pr = Wb + (long)(qt * 128 + row) * Sn + kt * 128 + cg;
        *(float4*)pr = z;
        *(float4*)(pr + 64) = z;
      }
    }
  }

  // ---- epilogue: ctx write ----
#pragma unroll
  for (int m = 0; m < 4; ++m)
#pragma unroll
    for (int n = 0; n < 4; ++n) {
      const int d = wn + n * 16 + lr;
#pragma unroll
      for (int r = 0; r < 4; ++r) {
        const int q = qt * 128 + wm + m * 16 + lg * 4 + r;
        ctx[(long)(b * Sn + q) * Dn + h * DH + d] = (bf16)acc[m][n][r];
      }
    }
}

extern "C" void kernel_launch(void* const* d_in, const int* in_sizes, int n_in,
                              void* d_out, int out_size, void* d_ws, size_t ws_size,
                              hipStream_t stream) {
  const float* hid = (const float*)d_in[0];
  const float* wq = (const float*)d_in[1];
  const float* wk = (const float*)d_in[2];
  const float* wv = (const float*)d_in[3];
  const float* wo = (const float*)d_in[4];
  const float* bo = (const float*)d_in[5];
  float* out = (float*)d_out;
  float* wts = out + (long)Bc * Sn * Dn;  // attn_weights region: [64][2048][2048] fp32

  char* ws = (char*)d_ws;
  const long MB = 1 << 20;
  bf16* h_hi = (bf16*)(ws + 0 * MB);
  bf16* h_lo = (bf16*)(ws + 32 * MB);
  bf16* wq_hi = (bf16*)(ws + 64 * MB);
  bf16* wq_lo = (bf16*)(ws + 72 * MB);
  bf16* wk_hi = (bf16*)(ws + 80 * MB);
  bf16* wk_lo = (bf16*)(ws + 88 * MB);
  bf16* wv_bf = (bf16*)(ws + 96 * MB);
  bf16* wo_bf = (bf16*)(ws + 104 * MB);
  bf16* q_hi = (bf16*)(ws + 112 * MB);
  bf16* q_lo = (bf16*)(ws + 144 * MB);
  bf16* k_hi = (bf16*)(ws + 176 * MB);
  bf16* k_lo = (bf16*)(ws + 208 * MB);
  bf16* vT = (bf16*)(ws + 240 * MB);
  bf16* ctx = (bf16*)(ws + 272 * MB);

  const long nH = (long)Bc * Sn * Dn;  // 16,777,216
  const long nW = (long)Dn * Dn;       // 4,194,304

  k_split<<<nH / 1024, 256, 0, stream>>>(hid, h_hi, h_lo, nH);
  k_split<<<nW / 1024, 256, 0, stream>>>(wq, wq_hi, wq_lo, nW);
  k_split<<<nW / 1024, 256, 0, stream>>>(wk, wk_hi, wk_lo, nW);
  k_cvt<<<nW / 1024, 256, 0, stream>>>(wv, wv_bf, nW);
  k_cvt<<<nW / 1024, 256, 0, stream>>>(wo, wo_bf, nW);

  // q = hid @ wq^T, k = hid @ wk^T   [8192 x 2048], split-bf16 outputs
  k_gemm_bt<3, 0, false><<<dim3(16, 64), 256, 0, stream>>>(
      h_hi, h_lo, Dn, wq_hi, wq_lo, Dn, Dn, q_hi, q_lo, nullptr, nullptr, Dn);
  k_gemm_bt<3, 0, false><<<dim3(16, 64), 256, 0, stream>>>(
      h_hi, h_lo, Dn, wk_hi, wk_lo, Dn, Dn, k_hi, k_lo, nullptr, nullptr, Dn);
  // vT = wv @ hid^T   [2048 x 8192] bf16 (v pre-transposed for PV's B operand)
  k_gemm_bt<1, 1, false><<<dim3(64, 16), 256, 0, stream>>>(
      wv_bf, nullptr, Dn, h_hi, nullptr, Dn, Dn, vT, nullptr, nullptr, nullptr, MROWS);
  // raw scores (lower-triangular tiles) straight into the attn_weights output region
  k_gemm_bt<3, 3, true><<<dim3(16, 16, 64), 256, 0, stream>>>(
      q_hi, q_lo, Dn, k_hi, k_lo, Dn, DH, nullptr, nullptr, wts, nullptr, Sn);
  // fused: causal softmax stats + normalized-weight write (incl. zero upper
  // triangle) + PV, one pass over the weights region
  k_wpv<<<dim3(16, 64), 256, 0, stream>>>(wts, vT, ctx);
  // out = ctx @ wo^T + bo
  k_gemm_bt<1, 2, false><<<dim3(16, 64), 256, 0, stream>>>(
      ctx, nullptr, Dn, wo_bf, nullptr, Dn, Dn, nullptr, nullptr, out, bo, Dn);
}

// Round 4
// 1384.971 us; speedup vs baseline: 1.7958x; 1.7958x over previous
//
#include <hip/hip_runtime.h>

#define DEVFN static __device__ __forceinline__

typedef __bf16 bf16;
typedef __bf16 bf16x8 __attribute__((ext_vector_type(8)));
typedef __bf16 bf16x4 __attribute__((ext_vector_type(4)));
typedef float f32x4 __attribute__((ext_vector_type(4)));
typedef short short8 __attribute__((ext_vector_type(8)));

constexpr int Bc = 4, Hn = 16, Sn = 2048, DH = 128, Dn = 2048;
constexpr long MROWS = (long)Bc * Sn;  // 8192

// ---------- MFMA wrapper: dual-signature dispatch ----------
template <typename T, typename C>
DEVFN auto mfma_impl(T a, T b, C c, int)
    -> decltype(__builtin_amdgcn_mfma_f32_16x16x32_bf16(a, b, c, 0, 0, 0)) {
  return __builtin_amdgcn_mfma_f32_16x16x32_bf16(a, b, c, 0, 0, 0);
}
template <typename T, typename C>
DEVFN C mfma_impl(T a, T b, C c, long) {
  return __builtin_amdgcn_mfma_f32_16x16x32_bf16(
      __builtin_bit_cast(short8, a), __builtin_bit_cast(short8, b), c, 0, 0, 0);
}
DEVFN f32x4 MFMA(bf16x8 a, bf16x8 b, f32x4 c) { return mfma_impl(a, b, c, 0); }

// ---------- async global->LDS 16B ----------
DEVFN void gld_lds16(const bf16* g, bf16* s) {
  __builtin_amdgcn_global_load_lds(
      (const __attribute__((address_space(1))) unsigned int*)g,
      (__attribute__((address_space(3))) unsigned int*)s, 16, 0, 0);
}

// Stage a 128x64 bf16 tile (row stride ld elems) into LDS, linear dest,
// source pre-swizzled so reads with byte^((row&7)<<4) are conflict-free.
DEVFN void stage_tile(const bf16* __restrict__ g, long ld, bf16* __restrict__ s) {
  const int t = threadIdx.x;
  const int rr = t >> 3;
  const int cb = (t & 7) * 16;  // byte offset within 128B row
#pragma unroll
  for (int ch = 0; ch < 4; ++ch) {
    const int r = ch * 32 + rr;
    const int scb = cb ^ ((r & 7) << 4);
    gld_lds16(g + (long)r * ld + (scb >> 1), s + r * 64 + (cb >> 1));
  }
}

// Swizzled fragment read: 8 contiguous bf16 at (tile-local row, k element), 64-col tile
DEVFN bf16x8 ldfrag(const bf16* s, int row, int kelem) {
  const int cb = (kelem * 2) ^ ((row & 7) << 4);
  return *(const bf16x8*)(s + row * 64 + (cb >> 1));
}

// 128-col bf16 tile variant (row stride 256 B)
DEVFN bf16x8 ldfrag128(const bf16* s, int row, int kelem) {
  const int cb = (kelem * 2) ^ ((row & 7) << 4);
  return *(const bf16x8*)((const char*)s + row * 256 + cb);
}

// ---------- split / convert ----------
__global__ __launch_bounds__(256) void k_split(const float* __restrict__ x,
                                               bf16* __restrict__ hi,
                                               bf16* __restrict__ lo, long n) {
  long i = ((long)blockIdx.x * blockDim.x + threadIdx.x) * 4;
  if (i >= n) return;
  float4 v = *(const float4*)(x + i);
  float a[4] = {v.x, v.y, v.z, v.w};
  bf16x4 h, l;
#pragma unroll
  for (int t = 0; t < 4; ++t) {
    bf16 hb = (bf16)a[t];
    h[t] = hb;
    l[t] = (bf16)(a[t] - (float)hb);
  }
  *(bf16x4*)(hi + i) = h;
  *(bf16x4*)(lo + i) = l;
}

__global__ __launch_bounds__(256) void k_cvt(const float* __restrict__ x,
                                             bf16* __restrict__ y, long n) {
  long i = ((long)blockIdx.x * blockDim.x + threadIdx.x) * 4;
  if (i >= n) return;
  float4 v = *(const float4*)(x + i);
  bf16x4 h;
  h[0] = (bf16)v.x; h[1] = (bf16)v.y; h[2] = (bf16)v.z; h[3] = (bf16)v.w;
  *(bf16x4*)(y + i) = h;
}

// ---------- generic C = A @ B^T  (both operands row-major, K contiguous) ----------
// PASSES: 1 = plain bf16, 3 = split-bf16 (hi*hi + hi*lo + lo*hi)
// OUTMODE: 0 = split bf16 pair, 1 = bf16, 2 = f32 + bias, 3 = f32
// CAUSAL: per-(b,h) QK^T, skip tiles above diagonal
template <int PASSES, int OUTMODE, bool CAUSAL>
__global__ __launch_bounds__(256) void k_gemm_bt(
    const bf16* __restrict__ Ahi, const bf16* __restrict__ Alo, long ldA,
    const bf16* __restrict__ Bhi, const bf16* __restrict__ Blo, long ldB, int K,
    bf16* __restrict__ obh, bf16* __restrict__ obl, float* __restrict__ of,
    const float* __restrict__ bias, long ldC) {
  const int nt = blockIdx.x, mt = blockIdx.y;
  long aBase = 0, bBase = 0, cBase = 0;
  if constexpr (CAUSAL) {
    if (nt > mt) return;
    const int bhz = blockIdx.z, b = bhz >> 4, h = bhz & 15;
    aBase = (long)b * Sn * ldA + h * DH;
    bBase = (long)b * Sn * ldB + h * DH;
    cBase = (long)bhz * Sn * Sn;
  }
  constexpr int NT = (PASSES == 3) ? 2 : 1;
  __shared__ __align__(16) bf16 sA[NT][128 * 64];
  __shared__ __align__(16) bf16 sB[NT][128 * 64];
  const int tid = threadIdx.x, w = tid >> 6, lane = tid & 63;
  const int wm = (w >> 1) * 64, wn = (w & 1) * 64;
  const int lr = lane & 15, lg = lane >> 4;
  f32x4 acc[4][4] = {};
  const bf16* Ab = Ahi + aBase + (long)mt * 128 * ldA;
  const bf16* Bb = Bhi + bBase + (long)nt * 128 * ldB;
  const bf16* AbL = (PASSES == 3) ? (Alo + aBase + (long)mt * 128 * ldA) : nullptr;
  const bf16* BbL = (PASSES == 3) ? (Blo + bBase + (long)nt * 128 * ldB) : nullptr;

  for (int kt = 0; kt < K; kt += 64) {
    stage_tile(Ab + kt, ldA, sA[0]);
    stage_tile(Bb + kt, ldB, sB[0]);
    if constexpr (PASSES == 3) {
      stage_tile(AbL + kt, ldA, sA[1]);
      stage_tile(BbL + kt, ldB, sB[1]);
    }
    __syncthreads();
#pragma unroll
    for (int kk = 0; kk < 64; kk += 32) {
      bf16x8 ahf[4], bhf[4], alf[4], blf[4];
#pragma unroll
      for (int m = 0; m < 4; ++m) ahf[m] = ldfrag(sA[0], wm + m * 16 + lr, kk + lg * 8);
#pragma unroll
      for (int n = 0; n < 4; ++n) bhf[n] = ldfrag(sB[0], wn + n * 16 + lr, kk + lg * 8);
      if constexpr (PASSES == 3) {
#pragma unroll
        for (int m = 0; m < 4; ++m) alf[m] = ldfrag(sA[1], wm + m * 16 + lr, kk + lg * 8);
#pragma unroll
        for (int n = 0; n < 4; ++n) blf[n] = ldfrag(sB[1], wn + n * 16 + lr, kk + lg * 8);
      }
#pragma unroll
      for (int m = 0; m < 4; ++m)
#pragma unroll
        for (int n = 0; n < 4; ++n) {
          acc[m][n] = MFMA(ahf[m], bhf[n], acc[m][n]);
          if constexpr (PASSES == 3) {
            acc[m][n] = MFMA(ahf[m], blf[n], acc[m][n]);
            acc[m][n] = MFMA(alf[m], bhf[n], acc[m][n]);
          }
        }
    }
    __syncthreads();
  }

#pragma unroll
  for (int m = 0; m < 4; ++m)
#pragma unroll
    for (int n = 0; n < 4; ++n) {
      const int col = nt * 128 + wn + n * 16 + lr;
#pragma unroll
      for (int r = 0; r < 4; ++r) {
        const long row = (long)mt * 128 + wm + m * 16 + lg * 4 + r;
        const float cv = acc[m][n][r];
        const long idx = cBase + row * ldC + col;
        if constexpr (OUTMODE == 0) {
          bf16 hv = (bf16)cv;
          obh[idx] = hv;
          obl[idx] = (bf16)(cv - (float)hv);
        } else if constexpr (OUTMODE == 1) {
          obh[idx] = (bf16)cv;
        } else if constexpr (OUTMODE == 2) {
          of[idx] = cv + bias[col];
        } else {
          of[idx] = cv;
        }
      }
    }
}

// ---------- wave reductions ----------
DEVFN float wred_max(float x) {
#pragma unroll
  for (int o = 32; o > 0; o >>= 1) x = fmaxf(x, __shfl_xor(x, o, 64));
  return x;
}
DEVFN float wred_sum(float x) {
#pragma unroll
  for (int o = 32; o > 0; o >>= 1) x += __shfl_xor(x, o, 64);
  return x;
}

// ---------- in-place causal row softmax; loads only the causal range ----------
__global__ __launch_bounds__(256) void k_softmax(float* __restrict__ wts) {
  const long row = blockIdx.x;
  const int qi = (int)(row & (Sn - 1));
  float* p = wts + row * Sn;
  const int tid = threadIdx.x, wv = tid >> 6, lane = tid & 63;
  const int j0 = tid * 8;
  const float NI = -__builtin_inff();
  float v[8];
  if (j0 <= qi) {
    float4 v0 = *(const float4*)(p + j0);
    float4 v1 = *(const float4*)(p + j0 + 4);
    v[0] = v0.x; v[1] = v0.y; v[2] = v0.z; v[3] = v0.w;
    v[4] = v1.x; v[5] = v1.y; v[6] = v1.z; v[7] = v1.w;
#pragma unroll
    for (int t = 0; t < 8; ++t)
      if (j0 + t > qi) v[t] = NI;
  } else {
#pragma unroll
    for (int t = 0; t < 8; ++t) v[t] = NI;
  }
  float mx = NI;
#pragma unroll
  for (int t = 0; t < 8; ++t) mx = fmaxf(mx, v[t]);
  mx = wred_max(mx);
  __shared__ float sm[4], ss[4];
  if (lane == 0) sm[wv] = mx;
  __syncthreads();
  mx = fmaxf(fmaxf(sm[0], sm[1]), fmaxf(sm[2], sm[3]));
  float s = 0.f;
#pragma unroll
  for (int t = 0; t < 8; ++t) {
    v[t] = __expf(v[t] - mx);
    s += v[t];
  }
  s = wred_sum(s);
  if (lane == 0) ss[wv] = s;
  __syncthreads();
  s = ss[0] + ss[1] + ss[2] + ss[3];
  const float inv = 1.f / s;
#pragma unroll
  for (int t = 0; t < 8; ++t) v[t] *= inv;
  *(float4*)(p + j0) = make_float4(v[0], v[1], v[2], v[3]);
  *(float4*)(p + j0 + 4) = make_float4(v[4], v[5], v[6], v[7]);
}

// ---------- PV with coalesced reg-prefetch + swizzled LDS staging ----------
// ctx[b,q,h*128+d] = sum_k W[bh][q][k] * vT[h*128+d][b*2048+k]
__global__ __launch_bounds__(256) void k_pv2(const float* __restrict__ wts,
                                             const bf16* __restrict__ vT,
                                             bf16* __restrict__ ctx) {
  const int qt = 15 - blockIdx.y;  // heavy tiles dispatched first
  const int bh = blockIdx.x, b = bh >> 4, h = bh & 15;
  const int tid = threadIdx.x, wv = tid >> 6, lane = tid & 63;
  const int lr = lane & 15, lg = lane >> 4;
  const int wm = (wv >> 1) * 64, wn = (wv & 1) * 64;
  const int rbase = tid >> 4;      // 0..15
  const int cg = (tid & 15) * 4;   // col group (fp32 elems) -> coalesced 256B/16 lanes
  const float* Wb = wts + (long)bh * Sn * Sn + (long)qt * 128 * Sn;
  const bf16* Vb = vT + (long)h * DH * MROWS + (long)b * Sn;
  __shared__ __align__(16) bf16 sW[128 * 128];
  f32x4 acc[4][4] = {};
  float4 pf[8][2];

  // prologue: prefetch tile 0
#pragma unroll
  for (int it = 0; it < 8; ++it) {
    const float* pr = Wb + (long)(it * 16 + rbase) * Sn + cg;
    pf[it][0] = *(const float4*)pr;
    pf[it][1] = *(const float4*)(pr + 64);
  }

  for (int kt = 0; kt <= qt; ++kt) {
    // convert prefetched tile -> swizzled LDS (sW free: first iter or post-MFMA sync)
#pragma unroll
    for (int it = 0; it < 8; ++it) {
      const int row = it * 16 + rbase;
      const int xr = (row & 7) << 4;
      bf16x4 c0, c1;
      float a0[4] = {pf[it][0].x, pf[it][0].y, pf[it][0].z, pf[it][0].w};
      float a1[4] = {pf[it][1].x, pf[it][1].y, pf[it][1].z, pf[it][1].w};
#pragma unroll
      for (int j = 0; j < 4; ++j) {
        c0[j] = (bf16)a0[j];
        c1[j] = (bf16)a1[j];
      }
      *(bf16x4*)((char*)sW + row * 256 + ((cg * 2) ^ xr)) = c0;
      *(bf16x4*)((char*)sW + row * 256 + (((cg + 64) * 2) ^ xr)) = c1;
    }
    // issue next tile's loads (overlap with this tile's MFMA phase)
    if (kt < qt) {
#pragma unroll
      for (int it = 0; it < 8; ++it) {
        const float* pr = Wb + (long)(it * 16 + rbase) * Sn + (kt + 1) * 128 + cg;
        pf[it][0] = *(const float4*)pr;
        pf[it][1] = *(const float4*)(pr + 64);
      }
    }
    __syncthreads();
#pragma unroll
    for (int kk = 0; kk < 128; kk += 32) {
      bf16x8 af[4], bfr[4];
#pragma unroll
      for (int m = 0; m < 4; ++m) af[m] = ldfrag128(sW, wm + m * 16 + lr, kk + lg * 8);
#pragma unroll
      for (int n = 0; n < 4; ++n)
        bfr[n] = *(const bf16x8*)(Vb + (long)(wn + n * 16 + lr) * MROWS + kt * 128 + kk + lg * 8);
#pragma unroll
      for (int m = 0; m < 4; ++m)
#pragma unroll
        for (int n = 0; n < 4; ++n) acc[m][n] = MFMA(af[m], bfr[n], acc[m][n]);
    }
    __syncthreads();
  }

#pragma unroll
  for (int m = 0; m < 4; ++m)
#pragma unroll
    for (int n = 0; n < 4; ++n) {
      const int d = wn + n * 16 + lr;
#pragma unroll
      for (int r = 0; r < 4; ++r) {
        const int q = qt * 128 + wm + m * 16 + lg * 4 + r;
        ctx[(long)(b * Sn + q) * Dn + h * DH + d] = (bf16)acc[m][n][r];
      }
    }
}

extern "C" void kernel_launch(void* const* d_in, const int* in_sizes, int n_in,
                              void* d_out, int out_size, void* d_ws, size_t ws_size,
                              hipStream_t stream) {
  const float* hid = (const float*)d_in[0];
  const float* wq = (const float*)d_in[1];
  const float* wk = (const float*)d_in[2];
  const float* wv = (const float*)d_in[3];
  const float* wo = (const float*)d_in[4];
  const float* bo = (const float*)d_in[5];
  float* out = (float*)d_out;
  float* wts = out + (long)Bc * Sn * Dn;  // attn_weights region: [64][2048][2048] fp32

  char* ws = (char*)d_ws;
  const long MB = 1 << 20;
  bf16* h_hi = (bf16*)(ws + 0 * MB);
  bf16* h_lo = (bf16*)(ws + 32 * MB);
  bf16* wq_hi = (bf16*)(ws + 64 * MB);
  bf16* wq_lo = (bf16*)(ws + 72 * MB);
  bf16* wk_hi = (bf16*)(ws + 80 * MB);
  bf16* wk_lo = (bf16*)(ws + 88 * MB);
  bf16* wv_bf = (bf16*)(ws + 96 * MB);
  bf16* wo_bf = (bf16*)(ws + 104 * MB);
  bf16* q_hi = (bf16*)(ws + 112 * MB);
  bf16* q_lo = (bf16*)(ws + 144 * MB);
  bf16* k_hi = (bf16*)(ws + 176 * MB);
  bf16* k_lo = (bf16*)(ws + 208 * MB);
  bf16* vT = (bf16*)(ws + 240 * MB);
  bf16* ctx = (bf16*)(ws + 272 * MB);

  const long nH = (long)Bc * Sn * Dn;  // 16,777,216
  const long nW = (long)Dn * Dn;       // 4,194,304

  k_split<<<nH / 1024, 256, 0, stream>>>(hid, h_hi, h_lo, nH);
  k_split<<<nW / 1024, 256, 0, stream>>>(wq, wq_hi, wq_lo, nW);
  k_split<<<nW / 1024, 256, 0, stream>>>(wk, wk_hi, wk_lo, nW);
  k_cvt<<<nW / 1024, 256, 0, stream>>>(wv, wv_bf, nW);
  k_cvt<<<nW / 1024, 256, 0, stream>>>(wo, wo_bf, nW);

  // q = hid @ wq^T, k = hid @ wk^T   [8192 x 2048], split-bf16 outputs
  k_gemm_bt<3, 0, false><<<dim3(16, 64), 256, 0, stream>>>(
      h_hi, h_lo, Dn, wq_hi, wq_lo, Dn, Dn, q_hi, q_lo, nullptr, nullptr, Dn);
  k_gemm_bt<3, 0, false><<<dim3(16, 64), 256, 0, stream>>>(
      h_hi, h_lo, Dn, wk_hi, wk_lo, Dn, Dn, k_hi, k_lo, nullptr, nullptr, Dn);
  // vT = wv @ hid^T   [2048 x 8192] bf16 (v pre-transposed for PV's B operand)
  k_gemm_bt<1, 1, false><<<dim3(64, 16), 256, 0, stream>>>(
      wv_bf, nullptr, Dn, h_hi, nullptr, Dn, Dn, vT, nullptr, nullptr, nullptr, MROWS);
  // raw scores (lower-triangular tiles) straight into the attn_weights output region
  k_gemm_bt<3, 3, true><<<dim3(16, 16, 64), 256, 0, stream>>>(
      q_hi, q_lo, Dn, k_hi, k_lo, Dn, DH, nullptr, nullptr, wts, nullptr, Sn);
  // in-place causal softmax (causal-range loads; writes exact zeros above diagonal)
  k_softmax<<<64 * Sn, 256, 0, stream>>>(wts);
  // ctx = W @ v  (coalesced staged weights, bf16 out, [B,S,D] layout)
  k_pv2<<<dim3(64, 16), 256, 0, stream>>>(wts, vT, ctx);
  // out = ctx @ wo^T + bo
  k_gemm_bt<1, 2, false><<<dim3(16, 64), 256, 0, stream>>>(
      ctx, nullptr, Dn, wo_bf, nullptr, Dn, Dn, nullptr, nullptr, out, bo, Dn);
}

// Round 5
// 1147.536 us; speedup vs baseline: 2.1674x; 1.2069x over previous
//
#include <hip/hip_runtime.h>

#define DEVFN static __device__ __forceinline__

typedef _Float16 f16;
typedef f16 f16x8 __attribute__((ext_vector_type(8)));
typedef f16 f16x4 __attribute__((ext_vector_type(4)));
typedef float f32x4 __attribute__((ext_vector_type(4)));
typedef short short8 __attribute__((ext_vector_type(8)));

constexpr int Bc = 4, Hn = 16, Sn = 2048, DH = 128, Dn = 2048;
constexpr long MROWS = (long)Bc * Sn;  // 8192

// ---------- MFMA wrapper: dual-signature dispatch (half8 preferred, short8 fallback) ----------
template <typename T, typename C>
DEVFN auto mfma_impl(T a, T b, C c, int)
    -> decltype(__builtin_amdgcn_mfma_f32_16x16x32_f16(a, b, c, 0, 0, 0)) {
  return __builtin_amdgcn_mfma_f32_16x16x32_f16(a, b, c, 0, 0, 0);
}
template <typename T, typename C>
DEVFN C mfma_impl(T a, T b, C c, long) {
  return __builtin_amdgcn_mfma_f32_16x16x32_f16(
      __builtin_bit_cast(short8, a), __builtin_bit_cast(short8, b), c, 0, 0, 0);
}
DEVFN f32x4 MFMA(f16x8 a, f16x8 b, f32x4 c) { return mfma_impl(a, b, c, 0); }

// ---------- async global->LDS 16B ----------
DEVFN void gld_lds16(const f16* g, f16* s) {
  __builtin_amdgcn_global_load_lds(
      (const __attribute__((address_space(1))) unsigned int*)g,
      (__attribute__((address_space(3))) unsigned int*)s, 16, 0, 0);
}

// Stage a 128x64 f16 tile (row stride ld elems) into LDS, linear dest,
// source pre-swizzled so reads with byte^((row&7)<<4) are conflict-free.
DEVFN void stage_tile(const f16* __restrict__ g, long ld, f16* __restrict__ s) {
  const int t = threadIdx.x;
  const int rr = t >> 3;
  const int cb = (t & 7) * 16;  // byte offset within 128B row
#pragma unroll
  for (int ch = 0; ch < 4; ++ch) {
    const int r = ch * 32 + rr;
    const int scb = cb ^ ((r & 7) << 4);
    gld_lds16(g + (long)r * ld + (scb >> 1), s + r * 64 + (cb >> 1));
  }
}

// Swizzled fragment read: 8 contiguous f16 at (tile-local row, k element), 64-col tile
DEVFN f16x8 ldfrag(const f16* s, int row, int kelem) {
  const int cb = (kelem * 2) ^ ((row & 7) << 4);
  return *(const f16x8*)(s + row * 64 + (cb >> 1));
}

// 128-col f16 tile variant (row stride 256 B)
DEVFN f16x8 ldfrag128(const f16* s, int row, int kelem) {
  const int cb = (kelem * 2) ^ ((row & 7) << 4);
  return *(const f16x8*)((const char*)s + row * 256 + cb);
}

// ---------- convert fp32 -> f16 ----------
__global__ __launch_bounds__(256) void k_cvt(const float* __restrict__ x,
                                             f16* __restrict__ y, long n) {
  long i = ((long)blockIdx.x * blockDim.x + threadIdx.x) * 4;
  if (i >= n) return;
  float4 v = *(const float4*)(x + i);
  f16x4 h;
  h[0] = (f16)v.x; h[1] = (f16)v.y; h[2] = (f16)v.z; h[3] = (f16)v.w;
  *(f16x4*)(y + i) = h;
}

// ---------- generic C = A @ B^T  (both operands row-major, K contiguous) ----------
// OUTMODE: 1 = f16, 2 = f32 + bias, 3 = f32
// CAUSAL: per-(b,h) QK^T, skip tiles above diagonal
template <int OUTMODE, bool CAUSAL>
__global__ __launch_bounds__(256) void k_gemm_bt(
    const f16* __restrict__ A, long ldA, const f16* __restrict__ B, long ldB,
    int K, f16* __restrict__ oh, float* __restrict__ of,
    const float* __restrict__ bias, long ldC) {
  const int nt = blockIdx.x, mt = blockIdx.y;
  long aBase = 0, bBase = 0, cBase = 0;
  if constexpr (CAUSAL) {
    if (nt > mt) return;
    const int bhz = blockIdx.z, b = bhz >> 4, h = bhz & 15;
    aBase = (long)b * Sn * ldA + h * DH;
    bBase = (long)b * Sn * ldB + h * DH;
    cBase = (long)bhz * Sn * Sn;
  }
  __shared__ __align__(16) f16 sA[128 * 64];
  __shared__ __align__(16) f16 sB[128 * 64];
  const int tid = threadIdx.x, w = tid >> 6, lane = tid & 63;
  const int wm = (w >> 1) * 64, wn = (w & 1) * 64;
  const int lr = lane & 15, lg = lane >> 4;
  f32x4 acc[4][4] = {};
  const f16* Ab = A + aBase + (long)mt * 128 * ldA;
  const f16* Bb = B + bBase + (long)nt * 128 * ldB;

  for (int kt = 0; kt < K; kt += 64) {
    stage_tile(Ab + kt, ldA, sA);
    stage_tile(Bb + kt, ldB, sB);
    __syncthreads();
#pragma unroll
    for (int kk = 0; kk < 64; kk += 32) {
      f16x8 ahf[4], bhf[4];
#pragma unroll
      for (int m = 0; m < 4; ++m) ahf[m] = ldfrag(sA, wm + m * 16 + lr, kk + lg * 8);
#pragma unroll
      for (int n = 0; n < 4; ++n) bhf[n] = ldfrag(sB, wn + n * 16 + lr, kk + lg * 8);
#pragma unroll
      for (int m = 0; m < 4; ++m)
#pragma unroll
        for (int n = 0; n < 4; ++n) acc[m][n] = MFMA(ahf[m], bhf[n], acc[m][n]);
    }
    __syncthreads();
  }

#pragma unroll
  for (int m = 0; m < 4; ++m)
#pragma unroll
    for (int n = 0; n < 4; ++n) {
      const int col = nt * 128 + wn + n * 16 + lr;
#pragma unroll
      for (int r = 0; r < 4; ++r) {
        const long row = (long)mt * 128 + wm + m * 16 + lg * 4 + r;
        const float cv = acc[m][n][r];
        const long idx = cBase + row * ldC + col;
        if constexpr (OUTMODE == 1) {
          oh[idx] = (f16)cv;
        } else if constexpr (OUTMODE == 2) {
          of[idx] = cv + bias[col];
        } else {
          of[idx] = cv;
        }
      }
    }
}

// ---------- wave reductions ----------
DEVFN float wred_max(float x) {
#pragma unroll
  for (int o = 32; o > 0; o >>= 1) x = fmaxf(x, __shfl_xor(x, o, 64));
  return x;
}
DEVFN float wred_sum(float x) {
#pragma unroll
  for (int o = 32; o > 0; o >>= 1) x += __shfl_xor(x, o, 64);
  return x;
}

// ---------- in-place causal row softmax; loads only the causal range ----------
__global__ __launch_bounds__(256) void k_softmax(float* __restrict__ wts) {
  const long row = blockIdx.x;
  const int qi = (int)(row & (Sn - 1));
  float* p = wts + row * Sn;
  const int tid = threadIdx.x, wv = tid >> 6, lane = tid & 63;
  const int j0 = tid * 8;
  const float NI = -__builtin_inff();
  float v[8];
  if (j0 <= qi) {
    float4 v0 = *(const float4*)(p + j0);
    float4 v1 = *(const float4*)(p + j0 + 4);
    v[0] = v0.x; v[1] = v0.y; v[2] = v0.z; v[3] = v0.w;
    v[4] = v1.x; v[5] = v1.y; v[6] = v1.z; v[7] = v1.w;
#pragma unroll
    for (int t = 0; t < 8; ++t)
      if (j0 + t > qi) v[t] = NI;
  } else {
#pragma unroll
    for (int t = 0; t < 8; ++t) v[t] = NI;
  }
  float mx = NI;
#pragma unroll
  for (int t = 0; t < 8; ++t) mx = fmaxf(mx, v[t]);
  mx = wred_max(mx);
  __shared__ float sm[4], ss[4];
  if (lane == 0) sm[wv] = mx;
  __syncthreads();
  mx = fmaxf(fmaxf(sm[0], sm[1]), fmaxf(sm[2], sm[3]));
  float s = 0.f;
#pragma unroll
  for (int t = 0; t < 8; ++t) {
    v[t] = __expf(v[t] - mx);
    s += v[t];
  }
  s = wred_sum(s);
  if (lane == 0) ss[wv] = s;
  __syncthreads();
  s = ss[0] + ss[1] + ss[2] + ss[3];
  const float inv = 1.f / s;
#pragma unroll
  for (int t = 0; t < 8; ++t) v[t] *= inv;
  *(float4*)(p + j0) = make_float4(v[0], v[1], v[2], v[3]);
  *(float4*)(p + j0 + 4) = make_float4(v[4], v[5], v[6], v[7]);
}

// ---------- PV with coalesced reg-prefetch + swizzled LDS staging ----------
// ctx[b,q,h*128+d] = sum_k W[bh][q][k] * vT[h*128+d][b*2048+k]
__global__ __launch_bounds__(256) void k_pv2(const float* __restrict__ wts,
                                             const f16* __restrict__ vT,
                                             f16* __restrict__ ctx) {
  const int qt = 15 - blockIdx.y;  // heavy tiles dispatched first
  const int bh = blockIdx.x, b = bh >> 4, h = bh & 15;
  const int tid = threadIdx.x, wv = tid >> 6, lane = tid & 63;
  const int lr = lane & 15, lg = lane >> 4;
  const int wm = (wv >> 1) * 64, wn = (wv & 1) * 64;
  const int rbase = tid >> 4;      // 0..15
  const int cg = (tid & 15) * 4;   // col group (fp32 elems) -> coalesced 256B/16 lanes
  const float* Wb = wts + (long)bh * Sn * Sn + (long)qt * 128 * Sn;
  const f16* Vb = vT + (long)h * DH * MROWS + (long)b * Sn;
  __shared__ __align__(16) f16 sW[128 * 128];
  f32x4 acc[4][4] = {};
  float4 pf[8][2];

  // prologue: prefetch tile 0
#pragma unroll
  for (int it = 0; it < 8; ++it) {
    const float* pr = Wb + (long)(it * 16 + rbase) * Sn + cg;
    pf[it][0] = *(const float4*)pr;
    pf[it][1] = *(const float4*)(pr + 64);
  }

  for (int kt = 0; kt <= qt; ++kt) {
    // convert prefetched tile -> swizzled LDS (sW free: first iter or post-MFMA sync)
#pragma unroll
    for (int it = 0; it < 8; ++it) {
      const int row = it * 16 + rbase;
      const int xr = (row & 7) << 4;
      f16x4 c0, c1;
      float a0[4] = {pf[it][0].x, pf[it][0].y, pf[it][0].z, pf[it][0].w};
      float a1[4] = {pf[it][1].x, pf[it][1].y, pf[it][1].z, pf[it][1].w};
#pragma unroll
      for (int j = 0; j < 4; ++j) {
        c0[j] = (f16)a0[j];
        c1[j] = (f16)a1[j];
      }
      *(f16x4*)((char*)sW + row * 256 + ((cg * 2) ^ xr)) = c0;
      *(f16x4*)((char*)sW + row * 256 + (((cg + 64) * 2) ^ xr)) = c1;
    }
    // issue next tile's loads (overlap with this tile's MFMA phase)
    if (kt < qt) {
#pragma unroll
      for (int it = 0; it < 8; ++it) {
        const float* pr = Wb + (long)(it * 16 + rbase) * Sn + (kt + 1) * 128 + cg;
        pf[it][0] = *(const float4*)pr;
        pf[it][1] = *(const float4*)(pr + 64);
      }
    }
    __syncthreads();
#pragma unroll
    for (int kk = 0; kk < 128; kk += 32) {
      f16x8 af[4], bfr[4];
#pragma unroll
      for (int m = 0; m < 4; ++m) af[m] = ldfrag128(sW, wm + m * 16 + lr, kk + lg * 8);
#pragma unroll
      for (int n = 0; n < 4; ++n)
        bfr[n] = *(const f16x8*)(Vb + (long)(wn + n * 16 + lr) * MROWS + kt * 128 + kk + lg * 8);
#pragma unroll
      for (int m = 0; m < 4; ++m)
#pragma unroll
        for (int n = 0; n < 4; ++n) acc[m][n] = MFMA(af[m], bfr[n], acc[m][n]);
    }
    __syncthreads();
  }

#pragma unroll
  for (int m = 0; m < 4; ++m)
#pragma unroll
    for (int n = 0; n < 4; ++n) {
      const int d = wn + n * 16 + lr;
#pragma unroll
      for (int r = 0; r < 4; ++r) {
        const int q = qt * 128 + wm + m * 16 + lg * 4 + r;
        ctx[(long)(b * Sn + q) * Dn + h * DH + d] = (f16)acc[m][n][r];
      }
    }
}

extern "C" void kernel_launch(void* const* d_in, const int* in_sizes, int n_in,
                              void* d_out, int out_size, void* d_ws, size_t ws_size,
                              hipStream_t stream) {
  const float* hid = (const float*)d_in[0];
  const float* wq = (const float*)d_in[1];
  const float* wk = (const float*)d_in[2];
  const float* wv = (const float*)d_in[3];
  const float* wo = (const float*)d_in[4];
  const float* bo = (const float*)d_in[5];
  float* out = (float*)d_out;
  float* wts = out + (long)Bc * Sn * Dn;  // attn_weights region: [64][2048][2048] fp32

  char* ws = (char*)d_ws;
  const long MB = 1 << 20;
  f16* h16 = (f16*)(ws + 0 * MB);     // 32 MB
  f16* wq16 = (f16*)(ws + 32 * MB);   // 8 MB
  f16* wk16 = (f16*)(ws + 40 * MB);
  f16* wv16 = (f16*)(ws + 48 * MB);
  f16* wo16 = (f16*)(ws + 56 * MB);
  f16* q16 = (f16*)(ws + 64 * MB);    // 32 MB
  f16* k16 = (f16*)(ws + 96 * MB);    // 32 MB
  f16* vT = (f16*)(ws + 128 * MB);    // 32 MB
  f16* ctx = (f16*)(ws + 160 * MB);   // 32 MB

  const long nH = (long)Bc * Sn * Dn;  // 16,777,216
  const long nW = (long)Dn * Dn;       // 4,194,304

  k_cvt<<<nH / 1024, 256, 0, stream>>>(hid, h16, nH);
  k_cvt<<<nW / 1024, 256, 0, stream>>>(wq, wq16, nW);
  k_cvt<<<nW / 1024, 256, 0, stream>>>(wk, wk16, nW);
  k_cvt<<<nW / 1024, 256, 0, stream>>>(wv, wv16, nW);
  k_cvt<<<nW / 1024, 256, 0, stream>>>(wo, wo16, nW);

  // q = hid @ wq^T, k = hid @ wk^T   [8192 x 2048] f16
  k_gemm_bt<1, false><<<dim3(16, 64), 256, 0, stream>>>(
      h16, Dn, wq16, Dn, Dn, q16, nullptr, nullptr, Dn);
  k_gemm_bt<1, false><<<dim3(16, 64), 256, 0, stream>>>(
      h16, Dn, wk16, Dn, Dn, k16, nullptr, nullptr, Dn);
  // vT = wv @ hid^T   [2048 x 8192] f16 (v pre-transposed for PV's B operand)
  k_gemm_bt<1, false><<<dim3(64, 16), 256, 0, stream>>>(
      wv16, Dn, h16, Dn, Dn, vT, nullptr, nullptr, MROWS);
  // raw scores (lower-triangular tiles) straight into the attn_weights output region
  k_gemm_bt<3, true><<<dim3(16, 16, 64), 256, 0, stream>>>(
      q16, Dn, k16, Dn, DH, nullptr, wts, nullptr, Sn);
  // in-place causal softmax (causal-range loads; writes exact zeros above diagonal)
  k_softmax<<<64 * Sn, 256, 0, stream>>>(wts);
  // ctx = W @ v  (coalesced staged weights, f16 out, [B,S,D] layout)
  k_pv2<<<dim3(64, 16), 256, 0, stream>>>(wts, vT, ctx);
  // out = ctx @ wo^T + bo
  k_gemm_bt<2, false><<<dim3(16, 64), 256, 0, stream>>>(
      ctx, Dn, wo16, Dn, Dn, nullptr, out, bo, Dn);
}

// Round 6
// 1015.798 us; speedup vs baseline: 2.4485x; 1.1297x over previous
//
#include <hip/hip_runtime.h>

#define DEVFN static __device__ __forceinline__

typedef _Float16 f16;
typedef f16 f16x8 __attribute__((ext_vector_type(8)));
typedef f16 f16x4 __attribute__((ext_vector_type(4)));
typedef float f32x4 __attribute__((ext_vector_type(4)));
typedef short short8 __attribute__((ext_vector_type(8)));

constexpr int Bc = 4, Hn = 16, Sn = 2048, DH = 128, Dn = 2048;
constexpr long MROWS = (long)Bc * Sn;  // 8192

// ---------- MFMA wrapper: dual-signature dispatch (half8 preferred, short8 fallback) ----------
template <typename T, typename C>
DEVFN auto mfma_impl(T a, T b, C c, int)
    -> decltype(__builtin_amdgcn_mfma_f32_16x16x32_f16(a, b, c, 0, 0, 0)) {
  return __builtin_amdgcn_mfma_f32_16x16x32_f16(a, b, c, 0, 0, 0);
}
template <typename T, typename C>
DEVFN C mfma_impl(T a, T b, C c, long) {
  return __builtin_amdgcn_mfma_f32_16x16x32_f16(
      __builtin_bit_cast(short8, a), __builtin_bit_cast(short8, b), c, 0, 0, 0);
}
DEVFN f32x4 MFMA(f16x8 a, f16x8 b, f32x4 c) { return mfma_impl(a, b, c, 0); }

// ---------- async global->LDS 16B ----------
DEVFN void gld_lds16(const f16* g, f16* s) {
  __builtin_amdgcn_global_load_lds(
      (const __attribute__((address_space(1))) unsigned int*)g,
      (__attribute__((address_space(3))) unsigned int*)s, 16, 0, 0);
}

// Stage a 128x64 f16 tile (row stride ld elems) into LDS, linear dest,
// source pre-swizzled so reads with byte^((row&7)<<4) are conflict-free.
DEVFN void stage_tile(const f16* __restrict__ g, long ld, f16* __restrict__ s) {
  const int t = threadIdx.x;
  const int rr = t >> 3;
  const int cb = (t & 7) * 16;  // byte offset within 128B row
#pragma unroll
  for (int ch = 0; ch < 4; ++ch) {
    const int r = ch * 32 + rr;
    const int scb = cb ^ ((r & 7) << 4);
    gld_lds16(g + (long)r * ld + (scb >> 1), s + r * 64 + (cb >> 1));
  }
}

// Stage a 128x128 f16 tile (row stride ld elems), same swizzle, 256B rows.
DEVFN void stage_tile128(const f16* __restrict__ g, long ld, f16* __restrict__ s) {
  const int t = threadIdx.x;
  const int rr = t >> 4;         // 0..15
  const int cb = (t & 15) * 16;  // byte col 0..255
#pragma unroll
  for (int ch = 0; ch < 8; ++ch) {
    const int r = ch * 16 + rr;
    const int scb = cb ^ ((r & 7) << 4);
    gld_lds16(g + (long)r * ld + (scb >> 1), s + r * 128 + (cb >> 1));
  }
}

// Swizzled fragment read: 8 contiguous f16 at (tile-local row, k element), 64-col tile
DEVFN f16x8 ldfrag(const f16* s, int row, int kelem) {
  const int cb = (kelem * 2) ^ ((row & 7) << 4);
  return *(const f16x8*)(s + row * 64 + (cb >> 1));
}

// 128-col f16 tile variant (row stride 256 B)
DEVFN f16x8 ldfrag128(const f16* s, int row, int kelem) {
  const int cb = (kelem * 2) ^ ((row & 7) << 4);
  return *(const f16x8*)((const char*)s + row * 256 + cb);
}

// ---------- convert fp32 -> f16 ----------
__global__ __launch_bounds__(256) void k_cvt(const float* __restrict__ x,
                                             f16* __restrict__ y, long n) {
  long i = ((long)blockIdx.x * blockDim.x + threadIdx.x) * 4;
  if (i >= n) return;
  float4 v = *(const float4*)(x + i);
  f16x4 h;
  h[0] = (f16)v.x; h[1] = (f16)v.y; h[2] = (f16)v.z; h[3] = (f16)v.w;
  *(f16x4*)(y + i) = h;
}

// ---------- generic C = A @ B^T  (both operands row-major, K contiguous) ----------
// OUTMODE: 1 = f16, 2 = f32 + bias
template <int OUTMODE>
__global__ __launch_bounds__(256) void k_gemm_bt(
    const f16* __restrict__ A, long ldA, const f16* __restrict__ B, long ldB,
    int K, f16* __restrict__ oh, float* __restrict__ of,
    const float* __restrict__ bias, long ldC) {
  const int nt = blockIdx.x, mt = blockIdx.y;
  __shared__ __align__(16) f16 sA[128 * 64];
  __shared__ __align__(16) f16 sB[128 * 64];
  const int tid = threadIdx.x, w = tid >> 6, lane = tid & 63;
  const int wm = (w >> 1) * 64, wn = (w & 1) * 64;
  const int lr = lane & 15, lg = lane >> 4;
  f32x4 acc[4][4] = {};
  const f16* Ab = A + (long)mt * 128 * ldA;
  const f16* Bb = B + (long)nt * 128 * ldB;

  for (int kt = 0; kt < K; kt += 64) {
    stage_tile(Ab + kt, ldA, sA);
    stage_tile(Bb + kt, ldB, sB);
    __syncthreads();
#pragma unroll
    for (int kk = 0; kk < 64; kk += 32) {
      f16x8 ahf[4], bhf[4];
#pragma unroll
      for (int m = 0; m < 4; ++m) ahf[m] = ldfrag(sA, wm + m * 16 + lr, kk + lg * 8);
#pragma unroll
      for (int n = 0; n < 4; ++n) bhf[n] = ldfrag(sB, wn + n * 16 + lr, kk + lg * 8);
#pragma unroll
      for (int m = 0; m < 4; ++m)
#pragma unroll
        for (int n = 0; n < 4; ++n) acc[m][n] = MFMA(ahf[m], bhf[n], acc[m][n]);
    }
    __syncthreads();
  }

#pragma unroll
  for (int m = 0; m < 4; ++m)
#pragma unroll
    for (int n = 0; n < 4; ++n) {
      const int col = nt * 128 + wn + n * 16 + lr;
#pragma unroll
      for (int r = 0; r < 4; ++r) {
        const long row = (long)mt * 128 + wm + m * 16 + lg * 4 + r;
        const float cv = acc[m][n][r];
        const long idx = row * ldC + col;
        if constexpr (OUTMODE == 1) {
          oh[idx] = (f16)cv;
        } else {
          of[idx] = cv + bias[col];
        }
      }
    }
}

// ---------- pass 1: QK^T + online causal row stats (no score write) ----------
// grid (bh=64, y=16 -> mt reversed). Block owns 128 q-rows; wave owns 32.
// stats[bh*2048 + q] = {row_max, 1/row_sum}
__global__ __launch_bounds__(256) void k_qkstats(const f16* __restrict__ q16,
                                                 const f16* __restrict__ k16,
                                                 float2* __restrict__ stats) {
  const int mt = 15 - (int)blockIdx.y;  // heavy first
  const int bh = blockIdx.x, b = bh >> 4, h = bh & 15;
  const int tid = threadIdx.x, wv = tid >> 6, lane = tid & 63;
  const int lr = lane & 15, lg = lane >> 4;
  const long base = (long)b * Sn * Dn + h * DH;
  const f16* Qb = q16 + base + (long)mt * 128 * Dn;
  const f16* Kb = k16 + base;
  __shared__ __align__(16) f16 sQ[128 * 128];
  __shared__ __align__(16) f16 sK[128 * 128];

  stage_tile128(Qb, Dn, sQ);
  __syncthreads();
  const int wq0 = wv * 32;
  f16x8 qf[2][4];
#pragma unroll
  for (int m = 0; m < 2; ++m)
#pragma unroll
    for (int kk = 0; kk < 4; ++kk)
      qf[m][kk] = ldfrag128(sQ, wq0 + m * 16 + lr, kk * 32 + lg * 8);

  const float NI = -__builtin_inff();
  float rm[2][4], rs[2][4];
#pragma unroll
  for (int m = 0; m < 2; ++m)
#pragma unroll
    for (int r = 0; r < 4; ++r) { rm[m][r] = NI; rs[m][r] = 0.f; }

  for (int kt = 0; kt <= mt; ++kt) {
    __syncthreads();  // all waves done reading sK from previous iter
    stage_tile128(Kb + (long)kt * 128 * Dn, Dn, sK);
    __syncthreads();
    f32x4 acc[2][8] = {};
#pragma unroll
    for (int kk = 0; kk < 4; ++kk) {
      f16x8 bf[8];
#pragma unroll
      for (int n = 0; n < 8; ++n) bf[n] = ldfrag128(sK, n * 16 + lr, kk * 32 + lg * 8);
#pragma unroll
      for (int m = 0; m < 2; ++m)
#pragma unroll
        for (int n = 0; n < 8; ++n) acc[m][n] = MFMA(qf[m][kk], bf[n], acc[m][n]);
    }
    const bool diag = (kt == mt);
#pragma unroll
    for (int m = 0; m < 2; ++m)
#pragma unroll
      for (int r = 0; r < 4; ++r) {
        const int row = wq0 + m * 16 + lg * 4 + r;  // tile-local q row
        float tm = NI;
#pragma unroll
        for (int n = 0; n < 8; ++n) {
          const bool ok = !diag || (n * 16 + lr) <= row;
          tm = fmaxf(tm, ok ? acc[m][n][r] : NI);
        }
#pragma unroll
        for (int o = 1; o < 16; o <<= 1) tm = fmaxf(tm, __shfl_xor(tm, o, 64));
        const float mnew = fmaxf(rm[m][r], tm);
        float ts = 0.f;
#pragma unroll
        for (int n = 0; n < 8; ++n) {
          const bool ok = !diag || (n * 16 + lr) <= row;
          ts += ok ? __expf(acc[m][n][r] - mnew) : 0.f;
        }
#pragma unroll
        for (int o = 1; o < 16; o <<= 1) ts += __shfl_xor(ts, o, 64);
        rs[m][r] = rs[m][r] * __expf(rm[m][r] - mnew) + ts;
        rm[m][r] = mnew;
      }
  }
  if (lr == 0) {
#pragma unroll
    for (int m = 0; m < 2; ++m)
#pragma unroll
      for (int r = 0; r < 4; ++r) {
        const int row = wq0 + m * 16 + lg * 4 + r;
        stats[(long)bh * Sn + mt * 128 + row] = make_float2(rm[m][r], 1.f / rs[m][r]);
      }
  }
}

// ---------- pass 2: recompute QK, normalize, write weights, PV ----------
// grid (bh=64, y=16 -> qt reversed). Wave owns 32 q-rows x 128 cols.
__global__ __launch_bounds__(256) void k_wpv2(
    const f16* __restrict__ q16, const f16* __restrict__ k16,
    const float2* __restrict__ stats, const f16* __restrict__ vT,
    float* __restrict__ wts, f16* __restrict__ ctx) {
  const int qt = 15 - (int)blockIdx.y;  // heavy first
  const int bh = blockIdx.x, b = bh >> 4, h = bh & 15;
  const int tid = threadIdx.x, wv = tid >> 6, lane = tid & 63;
  const int lr = lane & 15, lg = lane >> 4;
  const long base = (long)b * Sn * Dn + h * DH;
  const f16* Qb = q16 + base + (long)qt * 128 * Dn;
  const f16* Kb = k16 + base;
  const f16* Vb = vT + (long)h * DH * MROWS + (long)b * Sn;
  float* Wrow = wts + (long)bh * Sn * Sn + (long)qt * 128 * Sn;
  __shared__ __align__(16) f16 sQW[128 * 128];  // Q staging, then P (f16) stash
  __shared__ __align__(16) f16 sK[128 * 128];

  stage_tile128(Qb, Dn, sQW);
  __syncthreads();
  const int wq0 = wv * 32;
  f16x8 qf[2][4];
#pragma unroll
  for (int m = 0; m < 2; ++m)
#pragma unroll
    for (int kk = 0; kk < 4; ++kk)
      qf[m][kk] = ldfrag128(sQW, wq0 + m * 16 + lr, kk * 32 + lg * 8);
  float rm[2][4], ri[2][4];
#pragma unroll
  for (int m = 0; m < 2; ++m)
#pragma unroll
    for (int r = 0; r < 4; ++r) {
      const float2 st = stats[(long)bh * Sn + qt * 128 + wq0 + m * 16 + lg * 4 + r];
      rm[m][r] = st.x; ri[m][r] = st.y;
    }
  __syncthreads();  // sQW frags extracted; buffer now reusable as P stash

  f32x4 pacc[2][8] = {};
  for (int kt = 0; kt <= qt; ++kt) {
    stage_tile128(Kb + (long)kt * 128 * Dn, Dn, sK);
    __syncthreads();
    // QK^T
    f32x4 sacc[2][8] = {};
#pragma unroll
    for (int kk = 0; kk < 4; ++kk) {
      f16x8 bf[8];
#pragma unroll
      for (int n = 0; n < 8; ++n) bf[n] = ldfrag128(sK, n * 16 + lr, kk * 32 + lg * 8);
#pragma unroll
      for (int m = 0; m < 2; ++m)
#pragma unroll
        for (int n = 0; n < 8; ++n) sacc[m][n] = MFMA(qf[m][kk], bf[n], sacc[m][n]);
    }
    // normalize -> global fp32 weights + wave-private f16 stash in sQW
    const bool diag = (kt == qt);
#pragma unroll
    for (int m = 0; m < 2; ++m)
#pragma unroll
      for (int n = 0; n < 8; ++n) {
        const int col = n * 16 + lr;  // tile-local key col
#pragma unroll
        for (int r = 0; r < 4; ++r) {
          const int row = wq0 + m * 16 + lg * 4 + r;
          float w = __expf(sacc[m][n][r] - rm[m][r]) * ri[m][r];
          if (diag && col > row) w = 0.f;
          Wrow[(long)row * Sn + kt * 128 + col] = w;
          *(f16*)((char*)sQW + row * 256 + ((col * 2) ^ ((row & 7) << 4))) = (f16)w;
        }
      }
    __syncthreads();  // also guarantees all waves finished reading sK
    // PV accumulate: pacc += P(sQW rows wq0..wq0+31) x V(kt block)
#pragma unroll
    for (int kk = 0; kk < 4; ++kk) {
      f16x8 af[2], bfr[8];
#pragma unroll
      for (int m = 0; m < 2; ++m)
        af[m] = ldfrag128(sQW, wq0 + m * 16 + lr, kk * 32 + lg * 8);
#pragma unroll
      for (int n = 0; n < 8; ++n)
        bfr[n] = *(const f16x8*)(Vb + (long)(n * 16 + lr) * MROWS + kt * 128 + kk * 32 + lg * 8);
#pragma unroll
      for (int m = 0; m < 2; ++m)
#pragma unroll
        for (int n = 0; n < 8; ++n) pacc[m][n] = MFMA(af[m], bfr[n], pacc[m][n]);
    }
    // sQW rows are wave-private (each wave writes/reads only its own 32 rows),
    // so no barrier needed before next iteration overwrites them.
  }

  // zero tiles above the diagonal (cols (qt+1)*128 .. 2047)
  {
    const float4 z = make_float4(0.f, 0.f, 0.f, 0.f);
    for (int kt = qt + 1; kt < 16; ++kt) {
      float* pt = Wrow + kt * 128 + (tid & 31) * 4;
#pragma unroll
      for (int p = 0; p < 16; ++p) {
        const int row = p * 8 + (tid >> 5);
        *(float4*)(pt + (long)row * Sn) = z;
      }
    }
  }

  // ctx epilogue
#pragma unroll
  for (int m = 0; m < 2; ++m)
#pragma unroll
    for (int n = 0; n < 8; ++n) {
      const int d = n * 16 + lr;
#pragma unroll
      for (int r = 0; r < 4; ++r) {
        const int q = qt * 128 + wq0 + m * 16 + lg * 4 + r;
        ctx[(long)(b * Sn + q) * Dn + h * DH + d] = (f16)pacc[m][n][r];
      }
    }
}

extern "C" void kernel_launch(void* const* d_in, const int* in_sizes, int n_in,
                              void* d_out, int out_size, void* d_ws, size_t ws_size,
                              hipStream_t stream) {
  const float* hid = (const float*)d_in[0];
  const float* wq = (const float*)d_in[1];
  const float* wk = (const float*)d_in[2];
  const float* wv = (const float*)d_in[3];
  const float* wo = (const float*)d_in[4];
  const float* bo = (const float*)d_in[5];
  float* out = (float*)d_out;
  float* wts = out + (long)Bc * Sn * Dn;  // attn_weights region: [64][2048][2048] fp32

  char* ws = (char*)d_ws;
  const long MB = 1 << 20;
  f16* h16 = (f16*)(ws + 0 * MB);      // 32 MB
  f16* wq16 = (f16*)(ws + 32 * MB);    // 8 MB
  f16* wk16 = (f16*)(ws + 40 * MB);
  f16* wv16 = (f16*)(ws + 48 * MB);
  f16* wo16 = (f16*)(ws + 56 * MB);
  f16* q16 = (f16*)(ws + 64 * MB);     // 32 MB
  f16* k16 = (f16*)(ws + 96 * MB);     // 32 MB
  f16* vT = (f16*)(ws + 128 * MB);     // 32 MB
  f16* ctx = (f16*)(ws + 160 * MB);    // 32 MB
  float2* stats = (float2*)(ws + 192 * MB);  // 1 MB

  const long nH = (long)Bc * Sn * Dn;  // 16,777,216
  const long nW = (long)Dn * Dn;       // 4,194,304

  k_cvt<<<nH / 1024, 256, 0, stream>>>(hid, h16, nH);
  k_cvt<<<nW / 1024, 256, 0, stream>>>(wq, wq16, nW);
  k_cvt<<<nW / 1024, 256, 0, stream>>>(wk, wk16, nW);
  k_cvt<<<nW / 1024, 256, 0, stream>>>(wv, wv16, nW);
  k_cvt<<<nW / 1024, 256, 0, stream>>>(wo, wo16, nW);

  // q = hid @ wq^T, k = hid @ wk^T   [8192 x 2048] f16
  k_gemm_bt<1><<<dim3(16, 64), 256, 0, stream>>>(
      h16, Dn, wq16, Dn, Dn, q16, nullptr, nullptr, Dn);
  k_gemm_bt<1><<<dim3(16, 64), 256, 0, stream>>>(
      h16, Dn, wk16, Dn, Dn, k16, nullptr, nullptr, Dn);
  // vT = wv @ hid^T   [2048 x 8192] f16 (v pre-transposed for PV's B operand)
  k_gemm_bt<1><<<dim3(64, 16), 256, 0, stream>>>(
      wv16, Dn, h16, Dn, Dn, vT, nullptr, nullptr, MROWS);
  // pass 1: causal softmax stats only (scores recomputed later, never spilled)
  k_qkstats<<<dim3(64, 16), 256, 0, stream>>>(q16, k16, stats);
  // pass 2: recompute QK, normalize+write weights (incl. zero upper), PV
  k_wpv2<<<dim3(64, 16), 256, 0, stream>>>(q16, k16, stats, vT, wts, ctx);
  // out = ctx @ wo^T + bo
  k_gemm_bt<2><<<dim3(16, 64), 256, 0, stream>>>(
      ctx, Dn, wo16, Dn, Dn, nullptr, out, bo, Dn);
}